// Round 1
// baseline (25641.614 us; speedup 1.0000x reference)
//
#include <hip/hip_runtime.h>
#include <hip/hip_bf16.h>

#define TSTEPS 127
#define Bn 64
#define Sn 256
#define Hn 1024
#define En 512
#define Vn 32000
#define H4 4096
#define NVB 250      // 32000/128
#define MROWS 8128   // 127*64

typedef __hip_bfloat16 bf16;
typedef __attribute__((ext_vector_type(8))) short bf16x8;
typedef __attribute__((ext_vector_type(4))) float f32x4;

__device__ __forceinline__ float us2f(unsigned short u){
  union { float f; unsigned int i; } v; v.i = ((unsigned int)u) << 16; return v.f;
}
__device__ __forceinline__ unsigned short f2us(float f){
  __hip_bfloat16 h = __float2bfloat16(f);
  return *reinterpret_cast<unsigned short*>(&h);
}

// ---------------- prep kernels ----------------
__global__ void k_prep(const float* __restrict__ Watt, const float* __restrict__ Wu,
                       float* __restrict__ Wcat){
  int idx = blockIdx.x*256 + threadIdx.x;      // 2048*2048
  int n = idx >> 11, k = idx & 2047;
  Wcat[idx] = (n < 1024) ? Watt[idx] : Wu[(size_t)(n-1024)*3072 + k];
}

__global__ void k_embed(const int* __restrict__ ids, const float* __restrict__ Etgt,
                        float* __restrict__ Y){
  int idx = blockIdx.x*256 + threadIdx.x;      // 127*64*512
  int e = idx & 511;
  int tb = idx >> 9;
  int id = ids[tb];
  Y[idx] = Etgt[(size_t)id*512 + e];
}

// ---------------- MFMA GEMM: C = A(MxK,f32) @ Bm(NxK,f32)^T ----------------
union SharedU {
  struct { unsigned short a[128*72]; unsigned short b[128*72]; } st;
  float c[128*128];
};

__global__ __launch_bounds__(256) void k_gemm(
    const float* __restrict__ A, const float* __restrict__ Bm,
    int M, int N, int K, int Mreal, int mode,
    const float* __restrict__ bias,
    bf16* __restrict__ ep, bf16* __restrict__ vu,
    float* __restrict__ pm, float* __restrict__ ps,
    float* __restrict__ goldlog, const int* __restrict__ ids)
{
  __shared__ SharedU sm;
  const int tid = threadIdx.x;
  const int lane = tid & 63, w = tid >> 6;
  const int wm = w >> 1, wn = w & 1;
  const int n0 = blockIdx.x * 128, m0 = blockIdx.y * 128;
  f32x4 acc[4][4];
#pragma unroll
  for (int i=0;i<4;i++)
#pragma unroll
    for (int j=0;j<4;j++) acc[i][j] = (f32x4)(0.f);

  for (int k0 = 0; k0 < K; k0 += 64) {
    __syncthreads();
#pragma unroll
    for (int i=0;i<8;i++){
      int idx = tid + i*256;              // 2048 float4 slots
      int r = idx >> 4, c4 = idx & 15;
      int gm = m0 + r;
      float4 va = (gm < Mreal) ? *(const float4*)(&A[(size_t)gm*K + k0 + c4*4])
                               : make_float4(0.f,0.f,0.f,0.f);
      ushort4 sa; sa.x=f2us(va.x); sa.y=f2us(va.y); sa.z=f2us(va.z); sa.w=f2us(va.w);
      *(ushort4*)(&sm.st.a[r*72 + c4*4]) = sa;
      float4 vb = *(const float4*)(&Bm[(size_t)(n0+r)*K + k0 + c4*4]);
      ushort4 sb; sb.x=f2us(vb.x); sb.y=f2us(vb.y); sb.z=f2us(vb.z); sb.w=f2us(vb.w);
      *(ushort4*)(&sm.st.b[r*72 + c4*4]) = sb;
    }
    __syncthreads();
#pragma unroll
    for (int kk = 0; kk < 64; kk += 32) {
      bf16x8 af[4], bfr[4];
      int krow = kk + ((lane >> 4) << 3);
#pragma unroll
      for (int m4=0;m4<4;m4++){
        int row = wm*64 + m4*16 + (lane & 15);
        af[m4] = *(const bf16x8*)(&sm.st.a[row*72 + krow]);
      }
#pragma unroll
      for (int n4=0;n4<4;n4++){
        int row = wn*64 + n4*16 + (lane & 15);
        bfr[n4] = *(const bf16x8*)(&sm.st.b[row*72 + krow]);
      }
#pragma unroll
      for (int m4=0;m4<4;m4++)
#pragma unroll
        for (int n4=0;n4<4;n4++)
          acc[m4][n4] = __builtin_amdgcn_mfma_f32_16x16x32_bf16(af[m4], bfr[n4], acc[m4][n4], 0,0,0);
    }
  }
  __syncthreads();
#pragma unroll
  for (int m4=0;m4<4;m4++)
#pragma unroll
    for (int n4=0;n4<4;n4++)
#pragma unroll
      for (int i=0;i<4;i++){
        int row = wm*64 + m4*16 + ((lane>>4)<<2) + i;
        int col = wn*64 + n4*16 + (lane&15);
        sm.c[row*128 + col] = acc[m4][n4][i];
      }
  __syncthreads();

  if (mode == 0) {
    for (int idx = tid; idx < 128*128; idx += 256) {
      int row = idx >> 7, col = idx & 127;
      int gm = m0 + row, gn = n0 + col;
      float vv = sm.c[idx];
      if (gn < 1024) { vv += bias[gn]; ep[(size_t)gm*1024 + gn] = __float2bfloat16(vv); }
      else           { vu[(size_t)gm*1024 + (gn-1024)] = __float2bfloat16(vv); }
    }
  } else {
    if (tid < 128) {
      int row = tid, gm = m0 + row;
      if (gm < Mreal) {
        float mx = -1e30f;
        for (int j=0;j<128;j++){
          int col = (row + j) & 127;
          float x = sm.c[row*128+col] + bias[n0+col];
          mx = fmaxf(mx, x);
        }
        float sum = 0.f;
        for (int j=0;j<128;j++){
          int col = (row + j) & 127;
          float x = sm.c[row*128+col] + bias[n0+col];
          sum += expf(x - mx);
        }
        pm[(size_t)gm*NVB + blockIdx.x] = mx;
        ps[(size_t)gm*NVB + blockIdx.x] = sum;
        int g = ids[gm + 64];
        unsigned d = (unsigned)(g - n0);
        if (d < 128u) goldlog[gm] = sm.c[row*128 + (int)d] + bias[g];
      }
    }
  }
}

// ---------------- recurrence kernels ----------------
// gates partial GEMM: gates[b,j] over virtual K=2560 ([o_prev|Y_t|h]), K-split in 4
__global__ __launch_bounds__(256) void k_gates(
    const float* __restrict__ Wih, const float* __restrict__ Whh,
    const float* __restrict__ Yt, const float* __restrict__ hin,
    const float* __restrict__ o_prev, int isfirst, float* __restrict__ gpart)
{
  __shared__ float As[32*33];
  __shared__ float Ws_[32*33];
  int tid = threadIdx.x;
  int n0 = blockIdx.x*32, m0 = blockIdx.y*32;
  int kbeg = blockIdx.z*640;
  float a00=0.f,a01=0.f,a10=0.f,a11=0.f;
  int ty = tid >> 4, tx = tid & 15;
  for (int k0 = kbeg; k0 < kbeg+640; k0 += 32) {
    __syncthreads();
#pragma unroll
    for (int i=0;i<4;i++){
      int idx = tid + i*256;
      int r = idx >> 5, cc = idx & 31;
      int k = k0 + cc;
      int b = m0 + r;
      float av;
      if (k < 1024)        av = isfirst ? 0.f : o_prev[b*1024 + k];
      else if (k < 1536)   av = Yt[b*512 + (k-1024)];
      else                 av = hin[b*1024 + (k-1536)];
      As[r*33+cc] = av;
      int j = n0 + r;
      Ws_[r*33+cc] = (k < 1536) ? Wih[(size_t)j*1536 + k] : Whh[(size_t)j*1024 + (k-1536)];
    }
    __syncthreads();
#pragma unroll
    for (int kk=0;kk<32;kk++){
      float x0 = As[(ty*2)*33+kk],   x1 = As[(ty*2+1)*33+kk];
      float w0 = Ws_[(tx*2)*33+kk],  w1 = Ws_[(tx*2+1)*33+kk];
      a00 += x0*w0; a01 += x0*w1; a10 += x1*w0; a11 += x1*w1;
    }
  }
  float* gp = gpart + (size_t)blockIdx.z*Bn*H4;
  gp[(m0+ty*2)*H4 + n0+tx*2]     = a00;
  gp[(m0+ty*2)*H4 + n0+tx*2+1]   = a01;
  gp[(m0+ty*2+1)*H4 + n0+tx*2]   = a10;
  gp[(m0+ty*2+1)*H4 + n0+tx*2+1] = a11;
}

__global__ void k_lstm(const float* __restrict__ gpart, const float* __restrict__ cin,
                       float* __restrict__ h, float* __restrict__ hT, float* __restrict__ c)
{
  int idx = blockIdx.x*256 + threadIdx.x;     // 65536
  int b = idx >> 10, kk = idx & 1023;
  float gi=0.f, gf=0.f, gg=0.f, go=0.f;
#pragma unroll
  for (int z=0; z<4; z++){
    const float* gp = gpart + (size_t)z*Bn*H4 + (size_t)b*H4;
    gi += gp[kk]; gf += gp[kk+1024]; gg += gp[kk+2048]; go += gp[kk+3072];
  }
  gi = 1.f/(1.f+expf(-gi));
  gf = 1.f/(1.f+expf(-gf));
  gg = tanhf(gg);
  go = 1.f/(1.f+expf(-go));
  float cn = gf * cin[idx] + gi * gg;
  float hn = go * tanhf(cn);
  c[idx] = cn; h[idx] = hn; hT[kk*64 + b] = hn;
}

// blocks 0..63: attention (e_t, softmax, pa = alpha@Vu) per batch b
// blocks 64..191: phT = W_u[:,2048:] @ h_t  (2 j's per wave)
__global__ __launch_bounds__(256) void k_attn_ph(
    const bf16* __restrict__ ep, const bf16* __restrict__ vuu,
    const float* __restrict__ h, const float* __restrict__ hT,
    const float* __restrict__ Wu,
    float* __restrict__ pa, float* __restrict__ phT)
{
  __shared__ float hl[1024];
  __shared__ float el[256];
  __shared__ float red[8];
  int bx = blockIdx.x, tid = threadIdx.x;
  int lane = tid & 63, w = tid >> 6;
  if (bx < 64) {
    int b = bx;
    for (int i=tid;i<1024;i+=256) hl[i] = h[b*1024+i];
    __syncthreads();
    for (int s = w; s < 256; s += 4) {
      const unsigned short* row = (const unsigned short*)ep + ((size_t)(b*256+s))*1024;
      float acc = 0.f;
#pragma unroll
      for (int i=0;i<16;i++){
        int k = lane + 64*i;
        acc += us2f(row[k]) * hl[k];
      }
#pragma unroll
      for (int off=32; off; off>>=1) acc += __shfl_xor(acc, off);
      if (lane == 0) el[s] = acc;
    }
    __syncthreads();
    float x = el[tid];
    float m = x;
#pragma unroll
    for (int off=32; off; off>>=1) m = fmaxf(m, __shfl_xor(m, off));
    if (lane==0) red[w] = m;
    __syncthreads();
    m = fmaxf(fmaxf(red[0],red[1]), fmaxf(red[2],red[3]));
    float p = expf(x - m);
    float ss = p;
#pragma unroll
    for (int off=32; off; off>>=1) ss += __shfl_xor(ss, off);
    if (lane==0) red[4+w] = ss;
    __syncthreads();
    float tot = red[4]+red[5]+red[6]+red[7];
    el[tid] = p / tot;
    __syncthreads();
    for (int j = tid; j < 1024; j += 256) {
      float acc = 0.f;
      const unsigned short* vcol = (const unsigned short*)vuu + (size_t)b*256*1024 + j;
      for (int s=0; s<256; s++) acc += el[s] * us2f(vcol[(size_t)s*1024]);
      pa[b*1024 + j] = acc;
    }
  } else {
    int jg = bx - 64;                  // 0..127
    int j0 = jg*8 + w*2;
    const float* wr0 = Wu + (size_t)j0*3072 + 2048;
    const float* wr1 = wr0 + 3072;
    float s0=0.f, s1=0.f;
    for (int k=0;k<1024;k++){
      float hv = hT[k*64+lane];
      s0 += wr0[k]*hv; s1 += wr1[k]*hv;
    }
    phT[j0*64+lane] = s0; phT[(j0+1)*64+lane] = s1;
  }
}

__global__ void k_otanh(const float* __restrict__ pa, const float* __restrict__ phT,
                        float* __restrict__ o_prev, float* __restrict__ comb)
{
  int idx = blockIdx.x*256 + threadIdx.x;     // 65536, b-major
  int b = idx >> 10, j = idx & 1023;
  float v = tanhf(pa[idx] + phT[j*64 + b]);
  o_prev[idx] = v;
  comb[idx] = v;
}

// ---------------- final reduce ----------------
__global__ void k_reduce(const float* __restrict__ pm, const float* __restrict__ ps,
                         const float* __restrict__ goldlog, const int* __restrict__ ids,
                         float* __restrict__ out)
{
  int b = blockIdx.x, tid = threadIdx.x;
  int lane = tid & 63, w = tid >> 6;
  __shared__ float wacc[4];
  float accum = 0.f;
  for (int t = w; t < TSTEPS; t += 4) {
    int r = t*64 + b;
    const float* pmr = pm + (size_t)r*NVB;
    const float* psr = ps + (size_t)r*NVB;
    float mx = -1e30f;
    for (int p2 = lane; p2 < NVB; p2 += 64) mx = fmaxf(mx, pmr[p2]);
#pragma unroll
    for (int off=32; off; off>>=1) mx = fmaxf(mx, __shfl_xor(mx, off));
    float sm = 0.f;
    for (int p2 = lane; p2 < NVB; p2 += 64) sm += psr[p2] * expf(pmr[p2] - mx);
#pragma unroll
    for (int off=32; off; off>>=1) sm += __shfl_xor(sm, off);
    if (lane == 0) {
      int g = ids[r + 64];
      if (g != 0) accum += goldlog[r] - (mx + logf(sm));
    }
  }
  if (lane == 0) wacc[w] = accum;
  __syncthreads();
  if (tid == 0) out[b] = wacc[0]+wacc[1]+wacc[2]+wacc[3];
}

// ---------------- host ----------------
extern "C" void kernel_launch(void* const* d_in, const int* in_sizes, int n_in,
                              void* d_out, int out_size, void* d_ws, size_t ws_size,
                              hipStream_t stream)
{
  const int*   ids  = (const int*)d_in[0];
  const float* vc   = (const float*)d_in[1];
  const float* h0   = (const float*)d_in[2];
  const float* c0   = (const float*)d_in[3];
  const float* Etgt = (const float*)d_in[4];
  const float* Watt = (const float*)d_in[5];
  const float* batt = (const float*)d_in[6];
  const float* Wih  = (const float*)d_in[7];
  const float* Whh  = (const float*)d_in[8];
  const float* Wu   = (const float*)d_in[9];
  const float* Wv   = (const float*)d_in[10];
  const float* bv   = (const float*)d_in[11];
  float* out = (float*)d_out;

  char* p = (char*)d_ws;
  auto alloc = [&](size_t bytes)->char* {
    char* r = p; p += (bytes + 255) & ~(size_t)255; return r;
  };
  float* Y     = (float*)alloc((size_t)TSTEPS*Bn*En*4);       // 16.6 MB
  float* Wcat  = (float*)alloc((size_t)2048*2048*4);          // 16.8 MB
  bf16*  ep    = (bf16*) alloc((size_t)Bn*Sn*Hn*2);           // 33.6 MB
  bf16*  vuu   = (bf16*) alloc((size_t)Bn*Sn*Hn*2);           // 33.6 MB
  float* h     = (float*)alloc(65536*4);
  float* hT    = (float*)alloc(65536*4);
  float* c     = (float*)alloc(65536*4);
  float* oprev = (float*)alloc(65536*4);
  float* gpart = (float*)alloc((size_t)4*Bn*H4*4);            // 4 MB
  float* pa    = (float*)alloc(65536*4);
  float* phT   = (float*)alloc(65536*4);
  float* comb  = (float*)alloc((size_t)8192*Hn*4);            // 33.6 MB (padded rows unused)
  float* pm    = (float*)alloc((size_t)MROWS*NVB*4);          // 8.1 MB
  float* ps    = (float*)alloc((size_t)MROWS*NVB*4);          // 8.1 MB
  float* gl    = (float*)alloc((size_t)MROWS*4);

  k_prep<<<(2048*2048)/256, 256, 0, stream>>>(Watt, Wu, Wcat);
  k_embed<<<(TSTEPS*Bn*En)/256, 256, 0, stream>>>(ids, Etgt, Y);
  // enc_proj + Vu fused GEMM: M=16384, N=2048, K=2048
  k_gemm<<<dim3(16, 128), 256, 0, stream>>>(vc, Wcat, 16384, 2048, 2048, 16384,
      0, batt, ep, vuu, nullptr, nullptr, nullptr, nullptr);

  for (int t = 0; t < TSTEPS; t++) {
    k_gates<<<dim3(128, 2, 4), 256, 0, stream>>>(Wih, Whh, Y + (size_t)t*Bn*En,
        t ? h : h0, oprev, t==0 ? 1 : 0, gpart);
    k_lstm<<<256, 256, 0, stream>>>(gpart, t ? c : c0, h, hT, c);
    k_attn_ph<<<192, 256, 0, stream>>>(ep, vuu, h, hT, Wu, pa, phT);
    k_otanh<<<256, 256, 0, stream>>>(pa, phT, oprev, comb + (size_t)t*Bn*Hn);
  }

  // vocab GEMM: M=8192(pad of 8128), N=32000, K=1024, fused softmax partials
  k_gemm<<<dim3(NVB, 64), 256, 0, stream>>>(comb, Wv, 8192, 32000, 1024, MROWS,
      1, bv, nullptr, nullptr, pm, ps, gl, ids);
  k_reduce<<<64, 256, 0, stream>>>(pm, ps, gl, ids, out);
}